// Round 1
// baseline (881.230 us; speedup 1.0000x reference)
//
#include <hip/hip_runtime.h>
#include <hip/hip_bf16.h>

typedef __attribute__((ext_vector_type(8))) short short8;
typedef __attribute__((ext_vector_type(4))) float float4v;
typedef __attribute__((ext_vector_type(4))) unsigned int uint4v;
typedef __attribute__((ext_vector_type(4))) unsigned short ushort4v;
typedef __attribute__((ext_vector_type(8))) unsigned short ushort8v;

#define BB 2
#define SS 2048
#define DD 768
#define HH 12
#define DH 64

__device__ inline unsigned short f2bf(float f) {
  union { float f; unsigned int u; } x; x.f = f;
  unsigned int u = x.u;
  return (unsigned short)((u + 0x7fffu + ((u >> 16) & 1u)) >> 16); // RNE
}

// ---------------- convert fp32 -> bf16 (hidden + Wq/Wk/Wv concat) --------------
__global__ void convert_kernel(const float* __restrict__ hidden,
                               const float* __restrict__ Wq,
                               const float* __restrict__ Wk,
                               const float* __restrict__ Wv,
                               unsigned short* __restrict__ Abf,
                               unsigned short* __restrict__ Wbf) {
  const int HVEC = (BB * SS * DD) / 4;   // 786432
  const int WVEC = (DD * DD) / 4;        // 147456
  int idx = blockIdx.x * blockDim.x + threadIdx.x;
  if (idx >= HVEC + 3 * WVEC) return;
  const float* src;
  unsigned short* dst;
  int off;
  if (idx < HVEC) { src = hidden; dst = Abf; off = idx; }
  else {
    int j = idx - HVEC;
    int w = j / WVEC; off = j - w * WVEC;
    src = (w == 0) ? Wq : (w == 1) ? Wk : Wv;
    dst = Wbf + (size_t)w * DD * DD;
  }
  float4v v = ((const float4v*)src)[off];
  ushort4v o;
  o.x = f2bf(v.x); o.y = f2bf(v.y); o.z = f2bf(v.z); o.w = f2bf(v.w);
  ((ushort4v*)dst)[off] = o;
}

// ---------------- fused QKV projection: C[4096, 2304] = Abf * Wbf^T ------------
__global__ __launch_bounds__(256) void proj_kernel(
    const unsigned short* __restrict__ Abf,   // [4096][768]
    const unsigned short* __restrict__ Wbf,   // [2304][768]
    const float* __restrict__ bq, const float* __restrict__ bk,
    const float* __restrict__ bv,
    unsigned short* __restrict__ Qbf, unsigned short* __restrict__ Kbf,
    unsigned short* __restrict__ Vbf) {       // each [B*H][S][DH]
  __shared__ unsigned short Alds[128][72];
  __shared__ unsigned short Blds[128][72];
  const int t = threadIdx.x;
  const int w = t >> 6, lane = t & 63, id = lane & 15, q = lane >> 4;
  const int m0 = (blockIdx.x & 31) * 128;   // 32 m-tiles
  const int n0 = (blockIdx.x >> 5) * 128;   // 18 n-tiles
  const int wm = (w >> 1) * 64, wn = (w & 1) * 64;

  float4v acc[4][4];
#pragma unroll
  for (int i = 0; i < 4; ++i)
#pragma unroll
    for (int j = 0; j < 4; ++j) acc[i][j] = (float4v){0.f, 0.f, 0.f, 0.f};

  for (int k0 = 0; k0 < DD; k0 += 64) {
    uint4v areg[4], breg[4];
#pragma unroll
    for (int j = 0; j < 4; ++j) {
      int c = t + 256 * j;            // 0..1023 16B-chunks
      int row = c >> 3, cb = c & 7;
      areg[j] = *(const uint4v*)(Abf + (size_t)(m0 + row) * DD + k0 + cb * 8);
      breg[j] = *(const uint4v*)(Wbf + (size_t)(n0 + row) * DD + k0 + cb * 8);
    }
    __syncthreads();
#pragma unroll
    for (int j = 0; j < 4; ++j) {
      int c = t + 256 * j;
      int row = c >> 3, cb = c & 7;
      *(uint4v*)&Alds[row][cb * 8] = areg[j];
      *(uint4v*)&Blds[row][cb * 8] = breg[j];
    }
    __syncthreads();
#pragma unroll
    for (int kk = 0; kk < 2; ++kk) {
      short8 af[4], bfr[4];
#pragma unroll
      for (int i = 0; i < 4; ++i)
        af[i] = *(const short8*)&Alds[wm + i * 16 + id][kk * 32 + q * 8];
#pragma unroll
      for (int j = 0; j < 4; ++j)
        bfr[j] = *(const short8*)&Blds[wn + j * 16 + id][kk * 32 + q * 8];
#pragma unroll
      for (int i = 0; i < 4; ++i)
#pragma unroll
        for (int j = 0; j < 4; ++j)
          acc[i][j] = __builtin_amdgcn_mfma_f32_16x16x32_bf16(af[i], bfr[j], acc[i][j], 0, 0, 0);
    }
  }
  // epilogue: scatter to Q/K/V in [b*H+h][s][d] bf16
#pragma unroll
  for (int j = 0; j < 4; ++j) {
    int n = n0 + wn + j * 16 + id;
    int proj = n / DD, within = n - proj * DD;
    const float* bias = (proj == 0) ? bq : (proj == 1) ? bk : bv;
    float bias_v = bias[within];
    int h = within >> 6, d = within & 63;
    unsigned short* dst = (proj == 0) ? Qbf : (proj == 1) ? Kbf : Vbf;
#pragma unroll
    for (int i = 0; i < 4; ++i) {
#pragma unroll
      for (int r = 0; r < 4; ++r) {
        int m = m0 + wm + i * 16 + 4 * q + r;
        int b = m >> 11, s = m & 2047;
        dst[(((size_t)(b * HH + h) * SS + s) * DH + d)] = f2bf(acc[i][j][r] + bias_v);
      }
    }
  }
}

// ---------------- V transpose: Vbf[bh][s][d] -> Vt[bh][d][s] -------------------
__global__ __launch_bounds__(256) void transpose_v(
    const unsigned short* __restrict__ Vbf, unsigned short* __restrict__ Vt) {
  __shared__ unsigned short lds[64][72];
  int bid = blockIdx.x;            // BB*HH*32 = 768
  int bh = bid >> 5, sc = (bid & 31) * 64;
  const unsigned short* src = Vbf + ((size_t)bh * SS + sc) * DH;
  int t = threadIdx.x;
#pragma unroll
  for (int j = 0; j < 2; ++j) {
    int c = t + 256 * j; int row = c >> 3, cb = c & 7;
    *(uint4v*)&lds[row][cb * 8] = *(const uint4v*)(src + row * DH + cb * 8);
  }
  __syncthreads();
  unsigned short* dst = Vt + (size_t)bh * DH * SS + sc;
#pragma unroll
  for (int j = 0; j < 2; ++j) {
    int c = t + 256 * j; int d = c >> 3, s8 = (c & 7) * 8;
    ushort8v o;
#pragma unroll
    for (int u = 0; u < 8; ++u) o[u] = lds[s8 + u][d];
    *(ushort8v*)(dst + (size_t)d * SS + s8) = o;
  }
}

// ---------------- fused flash attention + RealFormer residual ------------------
__global__ __launch_bounds__(256) void attn_kernel(
    const unsigned short* __restrict__ Qbf,   // [bh][s][d]
    const unsigned short* __restrict__ Kbf,   // [bh][s][d]
    const unsigned short* __restrict__ Vt,    // [bh][d][s]
    const float* __restrict__ res,            // [bh][s][s]
    const float* __restrict__ mask,           // [b][s]
    float* __restrict__ ctx_out,              // [b][s][768]
    float* __restrict__ sc_out) {             // [bh][s][s]
  __shared__ unsigned short Plds[4][16][72];
  int bid = blockIdx.x;            // bh*32 + qt
  int bh = bid >> 5, qt = bid & 31;
  int b = bh / HH, h = bh - b * HH;
  int t = threadIdx.x, w = t >> 6, lane = t & 63, id = lane & 15, q = lane >> 4;

  const unsigned short* Qp = Qbf + ((size_t)bh * SS + qt * 64 + w * 16 + id) * DH;
  short8 qf0 = *(const short8*)(Qp + q * 8);
  short8 qf1 = *(const short8*)(Qp + 32 + q * 8);

  float m_i[4], l_i[4];
  float4v O[4];
#pragma unroll
  for (int r = 0; r < 4; ++r) { m_i[r] = -1e30f; l_i[r] = 0.f; }
#pragma unroll
  for (int j = 0; j < 4; ++j) O[j] = (float4v){0.f, 0.f, 0.f, 0.f};

  const float scale = 0.125f;
  const size_t row_base = ((size_t)bh * SS + qt * 64 + w * 16) * SS;

  for (int kc = 0; kc < 32; ++kc) {
    int c0 = kc * 64;
    float4v sacc[4];
#pragma unroll
    for (int tt = 0; tt < 4; ++tt) {
      const unsigned short* Kp = Kbf + ((size_t)bh * SS + c0 + tt * 16 + id) * DH;
      short8 kf0 = *(const short8*)(Kp + q * 8);
      short8 kf1 = *(const short8*)(Kp + 32 + q * 8);
      float4v a = (float4v){0.f, 0.f, 0.f, 0.f};
      a = __builtin_amdgcn_mfma_f32_16x16x32_bf16(qf0, kf0, a, 0, 0, 0);
      a = __builtin_amdgcn_mfma_f32_16x16x32_bf16(qf1, kf1, a, 0, 0, 0);
      sacc[tt] = a;
    }
    // scale + residual add, write scores_res_out, mask, row stats
    float sv[4][4];
    float rowmax[4];
#pragma unroll
    for (int r = 0; r < 4; ++r) rowmax[r] = -1e30f;
#pragma unroll
    for (int tt = 0; tt < 4; ++tt) {
      int col = c0 + tt * 16 + id;
      float maskv = mask[b * SS + col];
#pragma unroll
      for (int r = 0; r < 4; ++r) {
        size_t off = row_base + (size_t)(4 * q + r) * SS + col;
        float val = sacc[tt][r] * scale + res[off];
        sc_out[off] = val;                 // pre-mask residual output
        float mval = val + maskv;
        sv[tt][r] = mval;
        rowmax[r] = fmaxf(rowmax[r], mval);
      }
    }
#pragma unroll
    for (int r = 0; r < 4; ++r) {
      float v = rowmax[r];
      v = fmaxf(v, __shfl_xor(v, 1, 16));
      v = fmaxf(v, __shfl_xor(v, 2, 16));
      v = fmaxf(v, __shfl_xor(v, 4, 16));
      v = fmaxf(v, __shfl_xor(v, 8, 16));
      rowmax[r] = v;
    }
    float alpha[4], rsum[4];
#pragma unroll
    for (int r = 0; r < 4; ++r) {
      float mn = fmaxf(m_i[r], rowmax[r]);
      alpha[r] = __expf(m_i[r] - mn);
      m_i[r] = mn;
      rsum[r] = 0.f;
    }
#pragma unroll
    for (int tt = 0; tt < 4; ++tt) {
#pragma unroll
      for (int r = 0; r < 4; ++r) {
        float p = __expf(sv[tt][r] - m_i[r]);
        rsum[r] += p;
        Plds[w][4 * q + r][tt * 16 + id] = f2bf(p);
      }
    }
#pragma unroll
    for (int r = 0; r < 4; ++r) {
      float v = rsum[r];
      v += __shfl_xor(v, 1, 16);
      v += __shfl_xor(v, 2, 16);
      v += __shfl_xor(v, 4, 16);
      v += __shfl_xor(v, 8, 16);
      l_i[r] = l_i[r] * alpha[r] + v;
    }
#pragma unroll
    for (int j = 0; j < 4; ++j)
#pragma unroll
      for (int r = 0; r < 4; ++r) O[j][r] *= alpha[r];
    __syncthreads();
    short8 af0 = *(const short8*)&Plds[w][id][q * 8];
    short8 af1 = *(const short8*)&Plds[w][id][32 + q * 8];
#pragma unroll
    for (int j = 0; j < 4; ++j) {
      const unsigned short* Vp = Vt + ((size_t)bh * DH + j * 16 + id) * SS + c0;
      short8 vf0 = *(const short8*)(Vp + q * 8);
      short8 vf1 = *(const short8*)(Vp + 32 + q * 8);
      O[j] = __builtin_amdgcn_mfma_f32_16x16x32_bf16(af0, vf0, O[j], 0, 0, 0);
      O[j] = __builtin_amdgcn_mfma_f32_16x16x32_bf16(af1, vf1, O[j], 0, 0, 0);
    }
    __syncthreads();
  }
  // epilogue: ctx[b][s][h*64 + d]
#pragma unroll
  for (int j = 0; j < 4; ++j) {
    int d = h * 64 + j * 16 + id;
#pragma unroll
    for (int r = 0; r < 4; ++r) {
      int srow = qt * 64 + w * 16 + 4 * q + r;
      ctx_out[((size_t)b * SS + srow) * DD + d] = O[j][r] / l_i[r];
    }
  }
}

extern "C" void kernel_launch(void* const* d_in, const int* in_sizes, int n_in,
                              void* d_out, int out_size, void* d_ws, size_t ws_size,
                              hipStream_t stream) {
  const float* hidden = (const float*)d_in[0];
  const float* mask   = (const float*)d_in[1];
  const float* res    = (const float*)d_in[2];
  const float* Wq = (const float*)d_in[3];
  const float* bq = (const float*)d_in[4];
  const float* Wk = (const float*)d_in[5];
  const float* bk = (const float*)d_in[6];
  const float* Wv = (const float*)d_in[7];
  const float* bv = (const float*)d_in[8];

  char* ws = (char*)d_ws;
  unsigned short* Abf = (unsigned short*)(ws);                 //  6,291,456 B
  unsigned short* Wbf = (unsigned short*)(ws + 6291456);       //  3,538,944 B
  unsigned short* Qbf = (unsigned short*)(ws + 9830400);       //  6,291,456 B
  unsigned short* Kbf = (unsigned short*)(ws + 16121856);      //  6,291,456 B
  unsigned short* Vbf = (unsigned short*)(ws + 22413312);      //  6,291,456 B
  unsigned short* Vt  = (unsigned short*)(ws + 28704768);      //  6,291,456 B

  float* ctx = (float*)d_out;
  float* sc  = (float*)d_out + (size_t)BB * SS * DD;

  convert_kernel<<<4800, 256, 0, stream>>>(hidden, Wq, Wk, Wv, Abf, Wbf);
  proj_kernel<<<576, 256, 0, stream>>>(Abf, Wbf, bq, bk, bv, Qbf, Kbf, Vbf);
  transpose_v<<<768, 256, 0, stream>>>(Vbf, Vt);
  attn_kernel<<<768, 256, 0, stream>>>(Qbf, Kbf, Vt, res, mask, ctx, sc);
}